// Round 10
// baseline (2424.345 us; speedup 1.0000x reference)
//
#include <hip/hip_runtime.h>
#include <hip/hip_bf16.h>

// ContextualEncoder2: 5 GRU cells, N=16384, H=1024, INPUT=1088. fp32 in/out;
// compute bf16 MFMA + fp32 accumulate (threshold = 2% of max|ref| = 1.47e-2).
// R6 (resubmit; R9 bench lost to GPU acquisition timeout):
// counted-vmcnt pipelined schedule (T3+T4+T5) on R5's BM=256 packed structure.
// Evidence: R5 cut FETCH 37% with ZERO dur change -> not BW-bound. No pipe saturated
// (MFMA 36%, LDS ~60%, L1 ~50%, HBM 14%) -> lock-step __syncthreads (vmcnt(0) drain)
// phase bubbles with occupancy reg-capped at 8 waves/CU. Fix per guide T3/T4/T5:
//  - BK=32 tiles, FOUR LDS buffers (4 x 28KB = 112KB, same footprint)
//  - raw s_barrier + per-wave counted s_waitcnt vmcnt(N), never 0 in main loop
//  - waves 0-3 stage A (4 loads), waves 4-7 stage B (3 loads) -> uniform counts
//  - unified IH+HH K-loop (QN branch on tile index), setprio(1) around MFMA cluster
// Packed layout unchanged: fragment(32 rows,16 k) = contiguous 1KB block;
//   idx(row,k) = G*32K + (k>>4)*512 + ((k>>3)&1)*256 + (row&31)*8 + (k&7), G=row>>5.

typedef __bf16 bf16_8 __attribute__((ext_vector_type(8)));
typedef float  f32_16 __attribute__((ext_vector_type(16)));

#define NBUOY 16384
#define HID   1024
#define TBUF  14336   // 28 blocks * 512 elems per 32-K tile buffer (28 KB)

__device__ __forceinline__ void async16(const void* g, void* l) {
    __builtin_amdgcn_global_load_lds(
        (const __attribute__((address_space(1))) unsigned int*)g,
        (__attribute__((address_space(3))) unsigned int*)l, 16, 0, 0);
}
__device__ __forceinline__ float sigm(float x)  { return 1.f / (1.f + __expf(-x)); }
__device__ __forceinline__ float tanh_f(float x){ return 1.f - 2.f / (1.f + __expf(2.f * x)); }

#define WAITV(n) asm volatile("s_waitcnt vmcnt(" #n ")" ::: "memory")

// One 32-K tile of the fused GRU GEMM: 10 ds_read_b128 + 12 MFMA per wave.
// QN = acc index for the "n" quantity (2 = gi_n for IH tiles, 3 = gh_n for HH tiles).
template<int QN>
__device__ __forceinline__ void compute_tile(
    const __bf16* base, f32_16 acc[4][2], int wm, int wn, int lane)
{
    const bf16_8 a00 = *(const bf16_8*)(base + ((wm * 2 + 0) * 2 + 0) * 512 + lane * 8);
    const bf16_8 a10 = *(const bf16_8*)(base + ((wm * 2 + 1) * 2 + 0) * 512 + lane * 8);
    const bf16_8 br0 = *(const bf16_8*)(base + (16 + 0 * 4 + wn * 2 + 0) * 512 + lane * 8);
    const bf16_8 bz0 = *(const bf16_8*)(base + (16 + 1 * 4 + wn * 2 + 0) * 512 + lane * 8);
    const bf16_8 bn0 = *(const bf16_8*)(base + (16 + 2 * 4 + wn * 2 + 0) * 512 + lane * 8);
    const bf16_8 a01 = *(const bf16_8*)(base + ((wm * 2 + 0) * 2 + 1) * 512 + lane * 8);
    const bf16_8 a11 = *(const bf16_8*)(base + ((wm * 2 + 1) * 2 + 1) * 512 + lane * 8);
    const bf16_8 br1 = *(const bf16_8*)(base + (16 + 0 * 4 + wn * 2 + 1) * 512 + lane * 8);
    const bf16_8 bz1 = *(const bf16_8*)(base + (16 + 1 * 4 + wn * 2 + 1) * 512 + lane * 8);
    const bf16_8 bn1 = *(const bf16_8*)(base + (16 + 2 * 4 + wn * 2 + 1) * 512 + lane * 8);
    __builtin_amdgcn_s_setprio(1);
    acc[0][0]  = __builtin_amdgcn_mfma_f32_32x32x16_bf16(a00, br0, acc[0][0], 0, 0, 0);
    acc[0][1]  = __builtin_amdgcn_mfma_f32_32x32x16_bf16(a10, br0, acc[0][1], 0, 0, 0);
    acc[1][0]  = __builtin_amdgcn_mfma_f32_32x32x16_bf16(a00, bz0, acc[1][0], 0, 0, 0);
    acc[1][1]  = __builtin_amdgcn_mfma_f32_32x32x16_bf16(a10, bz0, acc[1][1], 0, 0, 0);
    acc[QN][0] = __builtin_amdgcn_mfma_f32_32x32x16_bf16(a00, bn0, acc[QN][0], 0, 0, 0);
    acc[QN][1] = __builtin_amdgcn_mfma_f32_32x32x16_bf16(a10, bn0, acc[QN][1], 0, 0, 0);
    acc[0][0]  = __builtin_amdgcn_mfma_f32_32x32x16_bf16(a01, br1, acc[0][0], 0, 0, 0);
    acc[0][1]  = __builtin_amdgcn_mfma_f32_32x32x16_bf16(a11, br1, acc[0][1], 0, 0, 0);
    acc[1][0]  = __builtin_amdgcn_mfma_f32_32x32x16_bf16(a01, bz1, acc[1][0], 0, 0, 0);
    acc[1][1]  = __builtin_amdgcn_mfma_f32_32x32x16_bf16(a11, bz1, acc[1][1], 0, 0, 0);
    acc[QN][0] = __builtin_amdgcn_mfma_f32_32x32x16_bf16(a01, bn1, acc[QN][0], 0, 0, 0);
    acc[QN][1] = __builtin_amdgcn_mfma_f32_32x32x16_bf16(a11, bn1, acc[QN][1], 0, 0, 0);
    __builtin_amdgcn_s_setprio(0);
}

// h_new = (1-z)*tanh(gi_n + r*gh_n') + z*h_prev
template<int KIH, int KHH, bool USE_E, bool OUT_F32>
__global__ __launch_bounds__(512, 2)
void gru_step(const __bf16* __restrict__ Aih, long aGS,    // packed A for IH tiles
              const __bf16* __restrict__ Wih,              // packed, KG=1088
              const __bf16* __restrict__ Ahh,              // packed X, KG=1088
              const __bf16* __restrict__ Whh,              // packed, KG=1024
              const float*  __restrict__ E,                // 100 x 3072 fp32 (has b_ih)
              const int*    __restrict__ ids,
              const float*  __restrict__ bih,
              const float*  __restrict__ bhh,
              const __bf16* __restrict__ hprev,            // packed X, KG=1088
              void* __restrict__ outp, long sOut)
{
    __shared__ __bf16 ls[4 * TBUF];        // 112 KB, 4 x 32-K tile buffers
    constexpr int NTIH = KIH / 32;
    constexpr int NT   = NTIH + KHH / 32;  // >= 2 for all instantiations
    const int tid  = threadIdx.x;
    const int lane = tid & 63, wid = tid >> 6;
    const int wm = wid >> 1, wn = wid & 1;
    const int l31 = lane & 31, hi = lane >> 5;
    // XCD-aware swizzle (kept from R5: FETCH -37%). bid%8 = XCD; each XCD owns a
    // 4x-by-32y super-tile. Bijective for 1024 blocks.
    const int bid = blockIdx.x;
    const int c = bid & 7, s = bid >> 3;
    const int xb = (c >> 1) * 4 + (s & 3);     // 0..15  (n-slice)
    const int yb = (c & 1) * 32 + (s >> 2);    // 0..63  (m-row group)
    const int aG0 = yb * 8;                // m0>>5  (8 groups of 32 rows per block)
    const int nG0 = xb * 2;                // n0>>5

    f32_16 acc[4][2];
    #pragma unroll
    for (int q = 0; q < 4; ++q)
        #pragma unroll
        for (int mt = 0; mt < 2; ++mt) acc[q][mt] = (f32_16)(0.0f);

    // stage one 32-K tile tt into buffer tt&3 (28 x 1KB fragment-blocks).
    // waves 0-3: A blocks 0..15 (4 each); waves 4-7: B blocks 0..11 (3 each).
    auto stage = [&](int tt) {
        if (tt >= NT) return;
        __bf16* dst = ls + (tt & 3) * TBUF;
        const __bf16* Ab; long aS; const __bf16* Wb; long wS; int kc2;
        if (tt < NTIH) { Ab = Aih; aS = aGS;   Wb = Wih; wS = 34816; kc2 = tt * 2; }
        else           { Ab = Ahh; aS = 34816; Wb = Whh; wS = 32768; kc2 = (tt - NTIH) * 2; }
        if (wid < 4) {
            #pragma unroll
            for (int i = 0; i < 4; ++i) {
                const int blk = wid * 4 + i;           // 0..15: g = blk>>1, kc = blk&1
                async16(Ab + (long)(aG0 + (blk >> 1)) * aS + (kc2 + (blk & 1)) * 512 + lane * 8,
                        dst + blk * 512);
            }
        } else {
            #pragma unroll
            for (int i = 0; i < 3; ++i) {
                const int u = (wid - 4) * 3 + i;       // 0..11: gate=u>>2, ng=(u>>1)&1, kc=u&1
                async16(Wb + (long)((u >> 2) * 32 + nG0 + ((u >> 1) & 1)) * wS
                           + (kc2 + (u & 1)) * 512 + lane * 8,
                        dst + (16 + u) * 512);
            }
        }
    };

    stage(0); stage(1);
    #pragma unroll 1
    for (int tt = 0; tt < NT - 1; ++tt) {
        stage(tt + 2);
        __builtin_amdgcn_sched_barrier(0);
        // counted wait: own tile-tt loads landed (oldest); tt+1/tt+2 stay in flight.
        if (wid < 4) { WAITV(4); } else { WAITV(3); }
        __builtin_amdgcn_s_barrier();          // all waves: buffer tt fully written
        __builtin_amdgcn_sched_barrier(0);
        const __bf16* base = ls + (tt & 3) * TBUF;
        if (tt < NTIH) compute_tile<2>(base, acc, wm, wn, lane);
        else           compute_tile<3>(base, acc, wm, wn, lane);
    }
    WAITV(0);                                  // last tile: drain everything
    __builtin_amdgcn_s_barrier();
    __builtin_amdgcn_sched_barrier(0);
    {
        const __bf16* base = ls + ((NT - 1) & 3) * TBUF;
        if (NT - 1 < NTIH) compute_tile<2>(base, acc, wm, wn, lane);
        else               compute_tile<3>(base, acc, wm, wn, lane);
    }

    // ---- epilogue: gates ----
    const int col = nG0 * 32 + wn * 32 + l31;      // 0..1023
    const float bhr = bhh[col], bhz = bhh[1024 + col], bhn = bhh[2048 + col];
    float cir = 0.f, ciz = 0.f, cin = 0.f;
    if (!USE_E) { cir = bih[col]; ciz = bih[1024 + col]; cin = bih[2048 + col]; }
    // lane-constant part of the packed offset for column `col` (K=1088 buffers)
    const long colPk = (long)(col >> 4) * 512 + ((col >> 3) & 1) * 256 + (col & 7);

    #pragma unroll
    for (int mt = 0; mt < 2; ++mt) {
        const int g = aG0 + wm * 2 + mt;           // 32-row group of this m-subtile
        #pragma unroll
        for (int reg = 0; reg < 16; ++reg) {
            const int r = 4 * hi + (reg & 3) + 8 * (reg >> 2);   // row within group
            const int row = g * 32 + r;
            float er = cir, ez = ciz, en = cin;
            if (USE_E) {
                const float* Ep = E + (long)ids[row] * 3072 + col;
                er = Ep[0]; ez = Ep[1024]; en = Ep[2048];
            }
            const float rr = sigm(acc[0][mt][reg] + er + bhr);
            const float z  = sigm(acc[1][mt][reg] + ez + bhz);
            const float nn = tanh_f(acc[2][mt][reg] + en + rr * (acc[3][mt][reg] + bhn));
            float hp = 0.f;
            if (KHH > 0) hp = (float)hprev[(long)g * 34816 + r * 8 + colPk];
            const float h = (1.f - z) * nn + z * hp;
            if (OUT_F32) ((float*)outp)[(long)row * sOut + col] = h;
            else        ((__bf16*)outp)[(long)g * 34816 + r * 8 + colPk] = (__bf16)h;
        }
    }
}

// Pack fp32 weight matrix (3072 x K row-major) -> packed bf16 (group stride 32K).
__global__ void pack_W(const float* __restrict__ W, __bf16* __restrict__ P, int K)
{
    const int q  = blockIdx.x * 256 + threadIdx.x;     // chunk id, 8 bf16 each
    const int kc = q % (K >> 3), row = q / (K >> 3);
    const float4 v0 = *(const float4*)(W + (long)row * K + kc * 8);
    const float4 v1 = *(const float4*)(W + (long)row * K + kc * 8 + 4);
    bf16_8 b;
    b[0] = (__bf16)v0.x; b[1] = (__bf16)v0.y; b[2] = (__bf16)v0.z; b[3] = (__bf16)v0.w;
    b[4] = (__bf16)v1.x; b[5] = (__bf16)v1.y; b[6] = (__bf16)v1.z; b[7] = (__bf16)v1.w;
    const long cidx = (long)(row >> 5) * (K * 4)
                    + (kc >> 1) * 64 + (kc & 1) * 32 + (row & 31);
    ((bf16_8*)P)[cidx] = b;
}

// Pack obs[:,t,:] into O0/O1/O2 (K=64 layout) and the obs pads of X0 (obs1) / X1 (obs2).
__global__ void build_obs(const float* __restrict__ obs,
                          __bf16* __restrict__ O0, __bf16* __restrict__ O1,
                          __bf16* __restrict__ O2,
                          __bf16* __restrict__ X0, __bf16* __restrict__ X1)
{
    const int q = blockIdx.x * 256 + threadIdx.x;      // 16384 rows x 24 chunks
    const int row = q / 24, c = q % 24;
    const int t = c >> 3, kc = c & 7;
    const float4 v0 = *(const float4*)(obs + (long)row * 512 + t * 64 + kc * 8);
    const float4 v1 = *(const float4*)(obs + (long)row * 512 + t * 64 + kc * 8 + 4);
    bf16_8 b;
    b[0] = (__bf16)v0.x; b[1] = (__bf16)v0.y; b[2] = (__bf16)v0.z; b[3] = (__bf16)v0.w;
    b[4] = (__bf16)v1.x; b[5] = (__bf16)v1.y; b[6] = (__bf16)v1.z; b[7] = (__bf16)v1.w;
    const int g = row >> 5, r = row & 31;
    const long ci = (long)g * 256 + (kc >> 1) * 64 + (kc & 1) * 32 + r;   // K=64
    __bf16* O = (t == 0) ? O0 : (t == 1) ? O1 : O2;
    ((bf16_8*)O)[ci] = b;
    // pads: cols 1024+kc*8 of the K=1088 packed X buffers
    const long cx = (long)g * 4352 + (64 + (kc >> 1)) * 64 + (kc & 1) * 32 + r;
    if (t == 1) ((bf16_8*)X0)[cx] = b;
    if (t == 2) ((bf16_8*)X1)[cx] = b;
}

// E[e][j] = b_ih[j] + sum_k emb[e,k]*W_ih[j][64+k], all fp32 (row-major, unchanged).
#define ETILE 10
__global__ void compute_E(const float* __restrict__ emb, const float* __restrict__ Wih,
                          const float* __restrict__ bih, float* __restrict__ E)
{
    __shared__ float semb[ETILE * 1024];   // 40 KB
    const int e0 = blockIdx.x * ETILE;
    const int j  = blockIdx.y * 256 + threadIdx.x;     // 0..3071
    for (int i = threadIdx.x; i < ETILE * 1024; i += 256)
        semb[i] = emb[(long)(e0 + (i >> 10)) * 1024 + (i & 1023)];
    __syncthreads();
    const float* wp = Wih + (long)j * 1088 + 64;
    float a[ETILE];
    const float b = bih[j];
    #pragma unroll
    for (int t = 0; t < ETILE; ++t) a[t] = b;
    for (int k = 0; k < 1024; k += 4) {
        const float4 w = *(const float4*)(wp + k);
        #pragma unroll
        for (int t = 0; t < ETILE; ++t) {
            const float* se = semb + t * 1024 + k;
            a[t] += se[0] * w.x + se[1] * w.y + se[2] * w.z + se[3] * w.w;
        }
    }
    #pragma unroll
    for (int t = 0; t < ETILE; ++t) E[(long)(e0 + t) * 3072 + j] = a[t];
}

extern "C" void kernel_launch(void* const* d_in, const int* in_sizes, int n_in,
                              void* d_out, int out_size, void* d_ws, size_t ws_size,
                              hipStream_t stream)
{
    const float* obs = (const float*)d_in[0];
    const int*   ids = (const int*)  d_in[1];
    const float* emb = (const float*)d_in[2];
    const float* Wih = (const float*)d_in[3];
    const float* Whh = (const float*)d_in[4];
    const float* bih = (const float*)d_in[5];
    const float* bhh = (const float*)d_in[6];
    float* out = (float*)d_out;

    const size_t MB = 1 << 20;
    const size_t XB = (size_t)NBUOY * 1088 * 2;        // 35,651,584
    const size_t NEEDED = 22 * MB + 3 * XB;            // ~124 MB
    if (ws_size < NEEDED) return;                      // diagnosable: absmax stays 0.734375

    char* ws = (char*)d_ws;
    float*  E    = (float*) ws;                        // 1.23 MB used (2 MB slot)
    __bf16* PWih = (__bf16*)(ws + 2 * MB);             // packed 3072x1088 bf16 (6.7 MB)
    __bf16* PWhh = (__bf16*)(ws + 9 * MB);             // packed 3072x1024 bf16 (6.3 MB)
    __bf16* O0   = (__bf16*)(ws + 16 * MB);            // packed 16384x64 (2 MB each)
    __bf16* O1   = (__bf16*)(ws + 18 * MB);
    __bf16* O2   = (__bf16*)(ws + 20 * MB);
    __bf16* X0   = (__bf16*)(ws + 22 * MB);            // packed 16384x1088
    __bf16* X1   = (__bf16*)(ws + 22 * MB + XB);
    __bf16* X2   = (__bf16*)(ws + 22 * MB + 2 * XB);

    dim3 blk(256);
    dim3 blkG(512);
    dim3 gridG(16 * 64);                               // 1-D, XCD-swizzled in-kernel

    pack_W<<<3072 * 1088 / 8 / 256, blk, 0, stream>>>(Wih, PWih, 1088);
    pack_W<<<3072 * 1024 / 8 / 256, blk, 0, stream>>>(Whh, PWhh, 1024);
    build_obs<<<NBUOY * 24 / 256, blk, 0, stream>>>(obs, O0, O1, O2, X0, X1);
    compute_E<<<dim3(10, 12), blk, 0, stream>>>(emb, Wih, bih, E);

    // step 0: x=[obs0|id_emb], h=0  -> h0 in X0 (packed)
    gru_step<64, 0, true, false><<<gridG, blkG, 0, stream>>>(
        O0, 2048, PWih, nullptr, PWhh, E, ids, bih, bhh, nullptr, X0, 0);
    // step 1: x=[obs1|id_emb], h=h0 -> h1 in X1
    gru_step<64, 1024, true, false><<<gridG, blkG, 0, stream>>>(
        O1, 2048, PWih, X0, PWhh, E, ids, bih, bhh, X0, X1, 0);
    // step 2: x=[obs2|id_emb], h=h1 -> h2 in X2
    gru_step<64, 1024, true, false><<<gridG, blkG, 0, stream>>>(
        O2, 2048, PWih, X1, PWhh, E, ids, bih, bhh, X1, X2, 0);
    // step 3: x=[h0|obs1] (=X0, pads hold obs1), h=h2 -> h3 in X1 (X1 pads already obs2)
    gru_step<1088, 1024, false, false><<<gridG, blkG, 0, stream>>>(
        X0, 34816, PWih, X2, PWhh, nullptr, ids, bih, bhh, X2, X1, 0);
    // step 4: x=[h3|obs2] (=X1), h=h3 -> fp32 d_out (row-major)
    gru_step<1088, 1024, false, true><<<gridG, blkG, 0, stream>>>(
        X1, 34816, PWih, X1, PWhh, nullptr, ids, bih, bhh, X1, out, 1024);
}

// Round 14
// 1490.491 us; speedup vs baseline: 1.6265x; 1.6265x over previous
//
#include <hip/hip_runtime.h>
#include <hip/hip_bf16.h>

// ContextualEncoder2: 5 GRU cells, N=16384, H=1024, INPUT=1088. fp32 in/out;
// compute bf16 MFMA + fp32 accumulate (threshold = 2% of max|ref| = 1.47e-2).
// R7 (resubmit x3; R11/R12/R13 benches lost to GPU acquisition timeouts):
// hybrid operand routing on the R5 skeleton (R6's asm-wait pipeline spilled to
// scratch: WRITE 65MB->1.97GB, MfmaUtil 8% -> reverted to __syncthreads-only sync).
// Pipe accounting (R5, per CU per 64-K tile): MFMA 1549 cyc, LDS 216KB ~ 2540 cyc,
// measured 4218 ~ their SUM (pipes serialize at 2 waves/SIMD lockstep). R3 (all-
// direct) was TCP-bound ~2500 -> same wall clock. Fix: split traffic across pipes:
//  - A: global_load_lds into double-buffered LDS (2 x 32KB), as in R5
//  - B (weights): direct global->VGPR, 1KB coalesced packed fragment per load,
//    L2-resident per-XCD W slice (R5 swizzle kept) -> LDS 96KB (~1130cyc),
//    TCP ~2000cyc, MFMA 1549cyc, three-way overlap.
// Packed layout unchanged: fragment(32 rows,16 k) = contiguous 1KB block;
//   idx(row,k) = G*32K + (k>>4)*512 + ((k>>3)&1)*256 + (row&31)*8 + (k&7), G=row>>5.

typedef __bf16 bf16_8 __attribute__((ext_vector_type(8)));
typedef float  f32_16 __attribute__((ext_vector_type(16)));

#define NBUOY 16384
#define HID   1024
#define ABUF  16384   // A: 32 blocks * 512 elems per 64-K tile buffer (32 KB)

__device__ __forceinline__ void async16(const void* g, void* l) {
    __builtin_amdgcn_global_load_lds(
        (const __attribute__((address_space(1))) unsigned int*)g,
        (__attribute__((address_space(3))) unsigned int*)l, 16, 0, 0);
}
__device__ __forceinline__ float sigm(float x)  { return 1.f / (1.f + __expf(-x)); }
__device__ __forceinline__ float tanh_f(float x){ return 1.f - 2.f / (1.f + __expf(2.f * x)); }

// One K-phase of the fused GRU GEMM. QN = acc index for this phase's "n" quantity
// (2 = gi_n for IH phase, 3 = gh_n for HH phase). aG0 = m0>>5, nG0 = n0>>5.
// buf = LDS buffer parity, carried across phases (cross-phase prefetch safety: the
// phase-prologue stage targets the buffer NOT read by the previous phase's final
// compute; the first barrier of this phase publishes it).
template<int QN, int K>
__device__ __forceinline__ void phase_hybrid(
    const __bf16* __restrict__ Ap, long aGS, int aG0,
    const __bf16* __restrict__ Wp, long wGS, int nG0,
    __bf16* ls, f32_16 acc[4][2], int tid, int& buf)
{
    const int lane = tid & 63, wid = tid >> 6;
    const int wm = wid >> 1, wn = wid & 1;
    constexpr int NT = K / 64;

    // stage one 64-K A-tile (32 x 1KB fragment-blocks) into buffer b; 4 loads/wave
    auto stageA = [&](int b, int t) {
        __bf16* dst = ls + b * ABUF;
        #pragma unroll
        for (int i = 0; i < 4; ++i) {
            const int blk = wid * 4 + i;               // g = blk>>2, kc = blk&3
            async16(Ap + (long)(aG0 + (blk >> 2)) * aGS + (t * 4 + (blk & 3)) * 512 + lane * 8,
                    dst + blk * 512);
        }
    };

    stageA(buf, 0);                     // prologue (overlaps prev phase's last compute)
    #pragma unroll 1
    for (int t = 0; t < NT; ++t) {
        __syncthreads();                // drains vmcnt: A-tile t staged; prev reads done
        if (t + 1 < NT) stageA(buf ^ 1, t + 1);
        // direct B loads for tile t: 12 x 1KB coalesced packed fragments (L2-hot).
        // Fully unrolled -> static indexing -> registers (rule #20).
        bf16_8 B[3][4];
        #pragma unroll
        for (int g = 0; g < 3; ++g)
            #pragma unroll
            for (int ks = 0; ks < 4; ++ks)
                B[g][ks] = *(const bf16_8*)(Wp + (long)(g * 32 + nG0 + wn) * wGS
                                               + (t * 4 + ks) * 512 + lane * 8);
        const __bf16* base = ls + buf * ABUF;
        #pragma unroll
        for (int ks = 0; ks < 4; ++ks) {
            const bf16_8 a0 = *(const bf16_8*)(base + ((wm * 2 + 0) * 4 + ks) * 512 + lane * 8);
            const bf16_8 a1 = *(const bf16_8*)(base + ((wm * 2 + 1) * 4 + ks) * 512 + lane * 8);
            acc[0][0]  = __builtin_amdgcn_mfma_f32_32x32x16_bf16(a0, B[0][ks], acc[0][0], 0, 0, 0);
            acc[0][1]  = __builtin_amdgcn_mfma_f32_32x32x16_bf16(a1, B[0][ks], acc[0][1], 0, 0, 0);
            acc[1][0]  = __builtin_amdgcn_mfma_f32_32x32x16_bf16(a0, B[1][ks], acc[1][0], 0, 0, 0);
            acc[1][1]  = __builtin_amdgcn_mfma_f32_32x32x16_bf16(a1, B[1][ks], acc[1][1], 0, 0, 0);
            acc[QN][0] = __builtin_amdgcn_mfma_f32_32x32x16_bf16(a0, B[2][ks], acc[QN][0], 0, 0, 0);
            acc[QN][1] = __builtin_amdgcn_mfma_f32_32x32x16_bf16(a1, B[2][ks], acc[QN][1], 0, 0, 0);
        }
        buf ^= 1;
    }
}

// h_new = (1-z)*tanh(gi_n + r*gh_n') + z*h_prev
template<int KIH, int KHH, bool USE_E, bool OUT_F32>
__global__ __launch_bounds__(512, 2)
void gru_step(const __bf16* __restrict__ Aih, long aGS,    // packed A for IH phase
              const __bf16* __restrict__ Wih,              // packed, KG=1088
              const __bf16* __restrict__ Ahh,              // packed X, KG=1088
              const __bf16* __restrict__ Whh,              // packed, KG=1024
              const float*  __restrict__ E,                // 100 x 3072 fp32 (has b_ih)
              const int*    __restrict__ ids,
              const float*  __restrict__ bih,
              const float*  __restrict__ bhh,
              const __bf16* __restrict__ hprev,            // packed X, KG=1088
              void* __restrict__ outp, long sOut)
{
    __shared__ __bf16 ls[2 * ABUF];        // 64 KB, A only, double-buffered
    const int tid  = threadIdx.x;
    const int lane = tid & 63, wid = tid >> 6;
    const int wm = wid >> 1, wn = wid & 1;
    const int l31 = lane & 31, hi = lane >> 5;
    // XCD-aware swizzle (kept from R5: FETCH -37%). bid%8 = XCD; each XCD owns a
    // 4x-by-32y super-tile. Bijective for 1024 blocks.
    const int bid = blockIdx.x;
    const int c = bid & 7, s = bid >> 3;
    const int xb = (c >> 1) * 4 + (s & 3);     // 0..15  (n-slice)
    const int yb = (c & 1) * 32 + (s >> 2);    // 0..63  (m-row group)
    const int aG0 = yb * 8;                // m0>>5  (8 groups of 32 rows per block)
    const int nG0 = xb * 2;                // n0>>5

    f32_16 acc[4][2];
    #pragma unroll
    for (int q = 0; q < 4; ++q)
        #pragma unroll
        for (int mt = 0; mt < 2; ++mt) acc[q][mt] = (f32_16)(0.0f);

    int buf = 0;
    phase_hybrid<2, KIH>(Aih, aGS, aG0, Wih, 34816, nG0, ls, acc, tid, buf);
    if (KHH > 0)
        phase_hybrid<3, KHH>(Ahh, 34816, aG0, Whh, 32768, nG0, ls, acc, tid, buf);

    // ---- epilogue: gates ----
    const int col = nG0 * 32 + wn * 32 + l31;      // 0..1023
    const float bhr = bhh[col], bhz = bhh[1024 + col], bhn = bhh[2048 + col];
    float cir = 0.f, ciz = 0.f, cin = 0.f;
    if (!USE_E) { cir = bih[col]; ciz = bih[1024 + col]; cin = bih[2048 + col]; }
    // lane-constant part of the packed offset for column `col` (K=1088 buffers)
    const long colPk = (long)(col >> 4) * 512 + ((col >> 3) & 1) * 256 + (col & 7);

    #pragma unroll
    for (int mt = 0; mt < 2; ++mt) {
        const int g = aG0 + wm * 2 + mt;           // 32-row group of this m-subtile
        #pragma unroll
        for (int reg = 0; reg < 16; ++reg) {
            const int r = 4 * hi + (reg & 3) + 8 * (reg >> 2);   // row within group
            const int row = g * 32 + r;
            float er = cir, ez = ciz, en = cin;
            if (USE_E) {
                const float* Ep = E + (long)ids[row] * 3072 + col;
                er = Ep[0]; ez = Ep[1024]; en = Ep[2048];
            }
            const float rr = sigm(acc[0][mt][reg] + er + bhr);
            const float z  = sigm(acc[1][mt][reg] + ez + bhz);
            const float nn = tanh_f(acc[2][mt][reg] + en + rr * (acc[3][mt][reg] + bhn));
            float hp = 0.f;
            if (KHH > 0) hp = (float)hprev[(long)g * 34816 + r * 8 + colPk];
            const float h = (1.f - z) * nn + z * hp;
            if (OUT_F32) ((float*)outp)[(long)row * sOut + col] = h;
            else        ((__bf16*)outp)[(long)g * 34816 + r * 8 + colPk] = (__bf16)h;
        }
    }
}

// Pack fp32 weight matrix (3072 x K row-major) -> packed bf16 (group stride 32K).
__global__ void pack_W(const float* __restrict__ W, __bf16* __restrict__ P, int K)
{
    const int q  = blockIdx.x * 256 + threadIdx.x;     // chunk id, 8 bf16 each
    const int kc = q % (K >> 3), row = q / (K >> 3);
    const float4 v0 = *(const float4*)(W + (long)row * K + kc * 8);
    const float4 v1 = *(const float4*)(W + (long)row * K + kc * 8 + 4);
    bf16_8 b;
    b[0] = (__bf16)v0.x; b[1] = (__bf16)v0.y; b[2] = (__bf16)v0.z; b[3] = (__bf16)v0.w;
    b[4] = (__bf16)v1.x; b[5] = (__bf16)v1.y; b[6] = (__bf16)v1.z; b[7] = (__bf16)v1.w;
    const long cidx = (long)(row >> 5) * (K * 4)
                    + (kc >> 1) * 64 + (kc & 1) * 32 + (row & 31);
    ((bf16_8*)P)[cidx] = b;
}

// Pack obs[:,t,:] into O0/O1/O2 (K=64 layout) and the obs pads of X0 (obs1) / X1 (obs2).
__global__ void build_obs(const float* __restrict__ obs,
                          __bf16* __restrict__ O0, __bf16* __restrict__ O1,
                          __bf16* __restrict__ O2,
                          __bf16* __restrict__ X0, __bf16* __restrict__ X1)
{
    const int q = blockIdx.x * 256 + threadIdx.x;      // 16384 rows x 24 chunks
    const int row = q / 24, c = q % 24;
    const int t = c >> 3, kc = c & 7;
    const float4 v0 = *(const float4*)(obs + (long)row * 512 + t * 64 + kc * 8);
    const float4 v1 = *(const float4*)(obs + (long)row * 512 + t * 64 + kc * 8 + 4);
    bf16_8 b;
    b[0] = (__bf16)v0.x; b[1] = (__bf16)v0.y; b[2] = (__bf16)v0.z; b[3] = (__bf16)v0.w;
    b[4] = (__bf16)v1.x; b[5] = (__bf16)v1.y; b[6] = (__bf16)v1.z; b[7] = (__bf16)v1.w;
    const int g = row >> 5, r = row & 31;
    const long ci = (long)g * 256 + (kc >> 1) * 64 + (kc & 1) * 32 + r;   // K=64
    __bf16* O = (t == 0) ? O0 : (t == 1) ? O1 : O2;
    ((bf16_8*)O)[ci] = b;
    // pads: cols 1024+kc*8 of the K=1088 packed X buffers
    const long cx = (long)g * 4352 + (64 + (kc >> 1)) * 64 + (kc & 1) * 32 + r;
    if (t == 1) ((bf16_8*)X0)[cx] = b;
    if (t == 2) ((bf16_8*)X1)[cx] = b;
}

// E[e][j] = b_ih[j] + sum_k emb[e,k]*W_ih[j][64+k], all fp32 (row-major, unchanged).
#define ETILE 10
__global__ void compute_E(const float* __restrict__ emb, const float* __restrict__ Wih,
                          const float* __restrict__ bih, float* __restrict__ E)
{
    __shared__ float semb[ETILE * 1024];   // 40 KB
    const int e0 = blockIdx.x * ETILE;
    const int j  = blockIdx.y * 256 + threadIdx.x;     // 0..3071
    for (int i = threadIdx.x; i < ETILE * 1024; i += 256)
        semb[i] = emb[(long)(e0 + (i >> 10)) * 1024 + (i & 1023)];
    __syncthreads();
    const float* wp = Wih + (long)j * 1088 + 64;
    float a[ETILE];
    const float b = bih[j];
    #pragma unroll
    for (int t = 0; t < ETILE; ++t) a[t] = b;
    for (int k = 0; k < 1024; k += 4) {
        const float4 w = *(const float4*)(wp + k);
        #pragma unroll
        for (int t = 0; t < ETILE; ++t) {
            const float* se = semb + t * 1024 + k;
            a[t] += se[0] * w.x + se[1] * w.y + se[2] * w.z + se[3] * w.w;
        }
    }
    #pragma unroll
    for (int t = 0; t < ETILE; ++t) E[(long)(e0 + t) * 3072 + j] = a[t];
}

extern "C" void kernel_launch(void* const* d_in, const int* in_sizes, int n_in,
                              void* d_out, int out_size, void* d_ws, size_t ws_size,
                              hipStream_t stream)
{
    const float* obs = (const float*)d_in[0];
    const int*   ids = (const int*)  d_in[1];
    const float* emb = (const float*)d_in[2];
    const float* Wih = (const float*)d_in[3];
    const float* Whh = (const float*)d_in[4];
    const float* bih = (const float*)d_in[5];
    const float* bhh = (const float*)d_in[6];
    float* out = (float*)d_out;

    const size_t MB = 1 << 20;
    const size_t XB = (size_t)NBUOY * 1088 * 2;        // 35,651,584
    const size_t NEEDED = 22 * MB + 3 * XB;            // ~124 MB
    if (ws_size < NEEDED) return;                      // diagnosable: absmax stays 0.734375

    char* ws = (char*)d_ws;
    float*  E    = (float*) ws;                        // 1.23 MB used (2 MB slot)
    __bf16* PWih = (__bf16*)(ws + 2 * MB);             // packed 3072x1088 bf16 (6.7 MB)
    __bf16* PWhh = (__bf16*)(ws + 9 * MB);             // packed 3072x1024 bf16 (6.3 MB)
    __bf16* O0   = (__bf16*)(ws + 16 * MB);            // packed 16384x64 (2 MB each)
    __bf16* O1   = (__bf16*)(ws + 18 * MB);
    __bf16* O2   = (__bf16*)(ws + 20 * MB);
    __bf16* X0   = (__bf16*)(ws + 22 * MB);            // packed 16384x1088
    __bf16* X1   = (__bf16*)(ws + 22 * MB + XB);
    __bf16* X2   = (__bf16*)(ws + 22 * MB + 2 * XB);

    dim3 blk(256);
    dim3 blkG(512);
    dim3 gridG(16 * 64);                               // 1-D, XCD-swizzled in-kernel

    pack_W<<<3072 * 1088 / 8 / 256, blk, 0, stream>>>(Wih, PWih, 1088);
    pack_W<<<3072 * 1024 / 8 / 256, blk, 0, stream>>>(Whh, PWhh, 1024);
    build_obs<<<NBUOY * 24 / 256, blk, 0, stream>>>(obs, O0, O1, O2, X0, X1);
    compute_E<<<dim3(10, 12), blk, 0, stream>>>(emb, Wih, bih, E);

    // step 0: x=[obs0|id_emb], h=0  -> h0 in X0 (packed)
    gru_step<64, 0, true, false><<<gridG, blkG, 0, stream>>>(
        O0, 2048, PWih, nullptr, PWhh, E, ids, bih, bhh, nullptr, X0, 0);
    // step 1: x=[obs1|id_emb], h=h0 -> h1 in X1
    gru_step<64, 1024, true, false><<<gridG, blkG, 0, stream>>>(
        O1, 2048, PWih, X0, PWhh, E, ids, bih, bhh, X0, X1, 0);
    // step 2: x=[obs2|id_emb], h=h1 -> h2 in X2
    gru_step<64, 1024, true, false><<<gridG, blkG, 0, stream>>>(
        O2, 2048, PWih, X1, PWhh, E, ids, bih, bhh, X1, X2, 0);
    // step 3: x=[h0|obs1] (=X0, pads hold obs1), h=h2 -> h3 in X1 (X1 pads already obs2)
    gru_step<1088, 1024, false, false><<<gridG, blkG, 0, stream>>>(
        X0, 34816, PWih, X2, PWhh, nullptr, ids, bih, bhh, X2, X1, 0);
    // step 4: x=[h3|obs2] (=X1), h=h3 -> fp32 d_out (row-major)
    gru_step<1088, 1024, false, true><<<gridG, blkG, 0, stream>>>(
        X1, 34816, PWih, X1, PWhh, nullptr, ids, bih, bhh, X1, out, 1024);
}

// Round 18
// 1001.649 us; speedup vs baseline: 2.4204x; 1.4880x over previous
//
#include <hip/hip_runtime.h>
#include <hip/hip_bf16.h>

// ContextualEncoder2: 5 GRU cells, N=16384, H=1024, INPUT=1088. fp32 in/out;
// compute bf16 MFMA + fp32 accumulate (threshold = 2% of max|ref| = 1.47e-2).
// R8 (resubmit x3; R15/R16/R17 benches lost to GPU acquisition timeouts):
// fix R7's broken overlap. R7 measured 384us/23% MfmaUtil: its B loads were
// issued AFTER the A-prefetch, and vmcnt is in-order, so the wait before the first
// MFMA (needs B) drained the A-prefetch too -> fully serial tile chain. Fix:
// register-double-buffer B: prefetch B(t+1) into named set Bn alongside stageA(t+1);
// compute tile t from Bc; copy Bc<-Bn (24 v_mov, static idx). No MFMA depends on
// this iteration's loads -> both prefetch streams stay in flight until the
// pre-barrier drain (R5's overlap profile) with LDS traffic 216->96 KB/tile.
//  - A: global_load_lds into double-buffered LDS (2 x 32KB)
//  - B: direct global->VGPR 1KB packed fragments, L2-hot per-XCD W slice (swizzle)
// Packed layout unchanged: fragment(32 rows,16 k) = contiguous 1KB block;
//   idx(row,k) = G*32K + (k>>4)*512 + ((k>>3)&1)*256 + (row&31)*8 + (k&7), G=row>>5.

typedef __bf16 bf16_8 __attribute__((ext_vector_type(8)));
typedef float  f32_16 __attribute__((ext_vector_type(16)));

#define NBUOY 16384
#define HID   1024
#define ABUF  16384   // A: 32 blocks * 512 elems per 64-K tile buffer (32 KB)

__device__ __forceinline__ void async16(const void* g, void* l) {
    __builtin_amdgcn_global_load_lds(
        (const __attribute__((address_space(1))) unsigned int*)g,
        (__attribute__((address_space(3))) unsigned int*)l, 16, 0, 0);
}
__device__ __forceinline__ float sigm(float x)  { return 1.f / (1.f + __expf(-x)); }
__device__ __forceinline__ float tanh_f(float x){ return 1.f - 2.f / (1.f + __expf(2.f * x)); }

// One K-phase of the fused GRU GEMM. QN = acc index for this phase's "n" quantity
// (2 = gi_n for IH phase, 3 = gh_n for HH phase). aG0 = m0>>5, nG0 = n0>>5.
// buf = LDS buffer parity, carried across phases (cross-phase prefetch safety: the
// phase-prologue stage targets the buffer NOT read by the previous phase's final
// compute; the first barrier of this phase publishes it).
template<int QN, int K>
__device__ __forceinline__ void phase_hybrid(
    const __bf16* __restrict__ Ap, long aGS, int aG0,
    const __bf16* __restrict__ Wp, long wGS, int nG0,
    __bf16* ls, f32_16 acc[4][2], int tid, int& buf)
{
    const int lane = tid & 63, wid = tid >> 6;
    const int wm = wid >> 1, wn = wid & 1;
    constexpr int NT = K / 64;

    // stage one 64-K A-tile (32 x 1KB fragment-blocks) into buffer b; 4 loads/wave
    auto stageA = [&](int b, int t) {
        __bf16* dst = ls + b * ABUF;
        #pragma unroll
        for (int i = 0; i < 4; ++i) {
            const int blk = wid * 4 + i;               // g = blk>>2, kc = blk&3
            async16(Ap + (long)(aG0 + (blk >> 2)) * aGS + (t * 4 + (blk & 3)) * 512 + lane * 8,
                    dst + blk * 512);
        }
    };
    // load one tile's B set (12 x 1KB coalesced packed fragments, L2-hot)
    auto loadB = [&](bf16_8 Bv[3][4], int t) {
        #pragma unroll
        for (int g = 0; g < 3; ++g)
            #pragma unroll
            for (int ks = 0; ks < 4; ++ks)
                Bv[g][ks] = *(const bf16_8*)(Wp + (long)(g * 32 + nG0 + wn) * wGS
                                                + (t * 4 + ks) * 512 + lane * 8);
    };

    bf16_8 Bc[3][4], Bn[3][4];          // current / next B register sets
    stageA(buf, 0);                     // prologue (overlaps prev phase's last compute)
    loadB(Bc, 0);
    #pragma unroll 1
    for (int t = 0; t < NT; ++t) {
        __syncthreads();                // drains vmcnt: A-tile t staged, Bc loaded
        if (t + 1 < NT) {
            stageA(buf ^ 1, t + 1);     // A prefetch: in flight across this compute
            loadB(Bn, t + 1);           // B prefetch: ditto (no MFMA below uses it)
        }
        const __bf16* base = ls + buf * ABUF;
        #pragma unroll
        for (int ks = 0; ks < 4; ++ks) {
            const bf16_8 a0 = *(const bf16_8*)(base + ((wm * 2 + 0) * 4 + ks) * 512 + lane * 8);
            const bf16_8 a1 = *(const bf16_8*)(base + ((wm * 2 + 1) * 4 + ks) * 512 + lane * 8);
            acc[0][0]  = __builtin_amdgcn_mfma_f32_32x32x16_bf16(a0, Bc[0][ks], acc[0][0], 0, 0, 0);
            acc[0][1]  = __builtin_amdgcn_mfma_f32_32x32x16_bf16(a1, Bc[0][ks], acc[0][1], 0, 0, 0);
            acc[1][0]  = __builtin_amdgcn_mfma_f32_32x32x16_bf16(a0, Bc[1][ks], acc[1][0], 0, 0, 0);
            acc[1][1]  = __builtin_amdgcn_mfma_f32_32x32x16_bf16(a1, Bc[1][ks], acc[1][1], 0, 0, 0);
            acc[QN][0] = __builtin_amdgcn_mfma_f32_32x32x16_bf16(a0, Bc[2][ks], acc[QN][0], 0, 0, 0);
            acc[QN][1] = __builtin_amdgcn_mfma_f32_32x32x16_bf16(a1, Bc[2][ks], acc[QN][1], 0, 0, 0);
        }
        if (t + 1 < NT) {
            #pragma unroll
            for (int g = 0; g < 3; ++g)
                #pragma unroll
                for (int ks = 0; ks < 4; ++ks)
                    Bc[g][ks] = Bn[g][ks];   // 24 v_mov; waits B(t+1) here, just
        }                                     // before the barrier would anyway
        buf ^= 1;
    }
}

// h_new = (1-z)*tanh(gi_n + r*gh_n') + z*h_prev
template<int KIH, int KHH, bool USE_E, bool OUT_F32>
__global__ __launch_bounds__(512, 2)
void gru_step(const __bf16* __restrict__ Aih, long aGS,    // packed A for IH phase
              const __bf16* __restrict__ Wih,              // packed, KG=1088
              const __bf16* __restrict__ Ahh,              // packed X, KG=1088
              const __bf16* __restrict__ Whh,              // packed, KG=1024
              const float*  __restrict__ E,                // 100 x 3072 fp32 (has b_ih)
              const int*    __restrict__ ids,
              const float*  __restrict__ bih,
              const float*  __restrict__ bhh,
              const __bf16* __restrict__ hprev,            // packed X, KG=1088
              void* __restrict__ outp, long sOut)
{
    __shared__ __bf16 ls[2 * ABUF];        // 64 KB, A only, double-buffered
    const int tid  = threadIdx.x;
    const int lane = tid & 63, wid = tid >> 6;
    const int wm = wid >> 1, wn = wid & 1;
    const int l31 = lane & 31, hi = lane >> 5;
    // XCD-aware swizzle (kept from R5: FETCH -37%). bid%8 = XCD; each XCD owns a
    // 4x-by-32y super-tile. Bijective for 1024 blocks.
    const int bid = blockIdx.x;
    const int c = bid & 7, s = bid >> 3;
    const int xb = (c >> 1) * 4 + (s & 3);     // 0..15  (n-slice)
    const int yb = (c & 1) * 32 + (s >> 2);    // 0..63  (m-row group)
    const int aG0 = yb * 8;                // m0>>5  (8 groups of 32 rows per block)
    const int nG0 = xb * 2;                // n0>>5

    f32_16 acc[4][2];
    #pragma unroll
    for (int q = 0; q < 4; ++q)
        #pragma unroll
        for (int mt = 0; mt < 2; ++mt) acc[q][mt] = (f32_16)(0.0f);

    int buf = 0;
    phase_hybrid<2, KIH>(Aih, aGS, aG0, Wih, 34816, nG0, ls, acc, tid, buf);
    if (KHH > 0)
        phase_hybrid<3, KHH>(Ahh, 34816, aG0, Whh, 32768, nG0, ls, acc, tid, buf);

    // ---- epilogue: gates ----
    const int col = nG0 * 32 + wn * 32 + l31;      // 0..1023
    const float bhr = bhh[col], bhz = bhh[1024 + col], bhn = bhh[2048 + col];
    float cir = 0.f, ciz = 0.f, cin = 0.f;
    if (!USE_E) { cir = bih[col]; ciz = bih[1024 + col]; cin = bih[2048 + col]; }
    // lane-constant part of the packed offset for column `col` (K=1088 buffers)
    const long colPk = (long)(col >> 4) * 512 + ((col >> 3) & 1) * 256 + (col & 7);

    #pragma unroll
    for (int mt = 0; mt < 2; ++mt) {
        const int g = aG0 + wm * 2 + mt;           // 32-row group of this m-subtile
        #pragma unroll
        for (int reg = 0; reg < 16; ++reg) {
            const int r = 4 * hi + (reg & 3) + 8 * (reg >> 2);   // row within group
            const int row = g * 32 + r;
            float er = cir, ez = ciz, en = cin;
            if (USE_E) {
                const float* Ep = E + (long)ids[row] * 3072 + col;
                er = Ep[0]; ez = Ep[1024]; en = Ep[2048];
            }
            const float rr = sigm(acc[0][mt][reg] + er + bhr);
            const float z  = sigm(acc[1][mt][reg] + ez + bhz);
            const float nn = tanh_f(acc[2][mt][reg] + en + rr * (acc[3][mt][reg] + bhn));
            float hp = 0.f;
            if (KHH > 0) hp = (float)hprev[(long)g * 34816 + r * 8 + colPk];
            const float h = (1.f - z) * nn + z * hp;
            if (OUT_F32) ((float*)outp)[(long)row * sOut + col] = h;
            else        ((__bf16*)outp)[(long)g * 34816 + r * 8 + colPk] = (__bf16)h;
        }
    }
}

// Pack fp32 weight matrix (3072 x K row-major) -> packed bf16 (group stride 32K).
__global__ void pack_W(const float* __restrict__ W, __bf16* __restrict__ P, int K)
{
    const int q  = blockIdx.x * 256 + threadIdx.x;     // chunk id, 8 bf16 each
    const int kc = q % (K >> 3), row = q / (K >> 3);
    const float4 v0 = *(const float4*)(W + (long)row * K + kc * 8);
    const float4 v1 = *(const float4*)(W + (long)row * K + kc * 8 + 4);
    bf16_8 b;
    b[0] = (__bf16)v0.x; b[1] = (__bf16)v0.y; b[2] = (__bf16)v0.z; b[3] = (__bf16)v0.w;
    b[4] = (__bf16)v1.x; b[5] = (__bf16)v1.y; b[6] = (__bf16)v1.z; b[7] = (__bf16)v1.w;
    const long cidx = (long)(row >> 5) * (K * 4)
                    + (kc >> 1) * 64 + (kc & 1) * 32 + (row & 31);
    ((bf16_8*)P)[cidx] = b;
}

// Pack obs[:,t,:] into O0/O1/O2 (K=64 layout) and the obs pads of X0 (obs1) / X1 (obs2).
__global__ void build_obs(const float* __restrict__ obs,
                          __bf16* __restrict__ O0, __bf16* __restrict__ O1,
                          __bf16* __restrict__ O2,
                          __bf16* __restrict__ X0, __bf16* __restrict__ X1)
{
    const int q = blockIdx.x * 256 + threadIdx.x;      // 16384 rows x 24 chunks
    const int row = q / 24, c = q % 24;
    const int t = c >> 3, kc = c & 7;
    const float4 v0 = *(const float4*)(obs + (long)row * 512 + t * 64 + kc * 8);
    const float4 v1 = *(const float4*)(obs + (long)row * 512 + t * 64 + kc * 8 + 4);
    bf16_8 b;
    b[0] = (__bf16)v0.x; b[1] = (__bf16)v0.y; b[2] = (__bf16)v0.z; b[3] = (__bf16)v0.w;
    b[4] = (__bf16)v1.x; b[5] = (__bf16)v1.y; b[6] = (__bf16)v1.z; b[7] = (__bf16)v1.w;
    const int g = row >> 5, r = row & 31;
    const long ci = (long)g * 256 + (kc >> 1) * 64 + (kc & 1) * 32 + r;   // K=64
    __bf16* O = (t == 0) ? O0 : (t == 1) ? O1 : O2;
    ((bf16_8*)O)[ci] = b;
    // pads: cols 1024+kc*8 of the K=1088 packed X buffers
    const long cx = (long)g * 4352 + (64 + (kc >> 1)) * 64 + (kc & 1) * 32 + r;
    if (t == 1) ((bf16_8*)X0)[cx] = b;
    if (t == 2) ((bf16_8*)X1)[cx] = b;
}

// E[e][j] = b_ih[j] + sum_k emb[e,k]*W_ih[j][64+k], all fp32 (row-major, unchanged).
#define ETILE 10
__global__ void compute_E(const float* __restrict__ emb, const float* __restrict__ Wih,
                          const float* __restrict__ bih, float* __restrict__ E)
{
    __shared__ float semb[ETILE * 1024];   // 40 KB
    const int e0 = blockIdx.x * ETILE;
    const int j  = blockIdx.y * 256 + threadIdx.x;     // 0..3071
    for (int i = threadIdx.x; i < ETILE * 1024; i += 256)
        semb[i] = emb[(long)(e0 + (i >> 10)) * 1024 + (i & 1023)];
    __syncthreads();
    const float* wp = Wih + (long)j * 1088 + 64;
    float a[ETILE];
    const float b = bih[j];
    #pragma unroll
    for (int t = 0; t < ETILE; ++t) a[t] = b;
    for (int k = 0; k < 1024; k += 4) {
        const float4 w = *(const float4*)(wp + k);
        #pragma unroll
        for (int t = 0; t < ETILE; ++t) {
            const float* se = semb + t * 1024 + k;
            a[t] += se[0] * w.x + se[1] * w.y + se[2] * w.z + se[3] * w.w;
        }
    }
    #pragma unroll
    for (int t = 0; t < ETILE; ++t) E[(long)(e0 + t) * 3072 + j] = a[t];
}

extern "C" void kernel_launch(void* const* d_in, const int* in_sizes, int n_in,
                              void* d_out, int out_size, void* d_ws, size_t ws_size,
                              hipStream_t stream)
{
    const float* obs = (const float*)d_in[0];
    const int*   ids = (const int*)  d_in[1];
    const float* emb = (const float*)d_in[2];
    const float* Wih = (const float*)d_in[3];
    const float* Whh = (const float*)d_in[4];
    const float* bih = (const float*)d_in[5];
    const float* bhh = (const float*)d_in[6];
    float* out = (float*)d_out;

    const size_t MB = 1 << 20;
    const size_t XB = (size_t)NBUOY * 1088 * 2;        // 35,651,584
    const size_t NEEDED = 22 * MB + 3 * XB;            // ~124 MB
    if (ws_size < NEEDED) return;                      // diagnosable: absmax stays 0.734375

    char* ws = (char*)d_ws;
    float*  E    = (float*) ws;                        // 1.23 MB used (2 MB slot)
    __bf16* PWih = (__bf16*)(ws + 2 * MB);             // packed 3072x1088 bf16 (6.7 MB)
    __bf16* PWhh = (__bf16*)(ws + 9 * MB);             // packed 3072x1024 bf16 (6.3 MB)
    __bf16* O0   = (__bf16*)(ws + 16 * MB);            // packed 16384x64 (2 MB each)
    __bf16* O1   = (__bf16*)(ws + 18 * MB);
    __bf16* O2   = (__bf16*)(ws + 20 * MB);
    __bf16* X0   = (__bf16*)(ws + 22 * MB);            // packed 16384x1088
    __bf16* X1   = (__bf16*)(ws + 22 * MB + XB);
    __bf16* X2   = (__bf16*)(ws + 22 * MB + 2 * XB);

    dim3 blk(256);
    dim3 blkG(512);
    dim3 gridG(16 * 64);                               // 1-D, XCD-swizzled in-kernel

    pack_W<<<3072 * 1088 / 8 / 256, blk, 0, stream>>>(Wih, PWih, 1088);
    pack_W<<<3072 * 1024 / 8 / 256, blk, 0, stream>>>(Whh, PWhh, 1024);
    build_obs<<<NBUOY * 24 / 256, blk, 0, stream>>>(obs, O0, O1, O2, X0, X1);
    compute_E<<<dim3(10, 12), blk, 0, stream>>>(emb, Wih, bih, E);

    // step 0: x=[obs0|id_emb], h=0  -> h0 in X0 (packed)
    gru_step<64, 0, true, false><<<gridG, blkG, 0, stream>>>(
        O0, 2048, PWih, nullptr, PWhh, E, ids, bih, bhh, nullptr, X0, 0);
    // step 1: x=[obs1|id_emb], h=h0 -> h1 in X1
    gru_step<64, 1024, true, false><<<gridG, blkG, 0, stream>>>(
        O1, 2048, PWih, X0, PWhh, E, ids, bih, bhh, X0, X1, 0);
    // step 2: x=[obs2|id_emb], h=h1 -> h2 in X2
    gru_step<64, 1024, true, false><<<gridG, blkG, 0, stream>>>(
        O2, 2048, PWih, X1, PWhh, E, ids, bih, bhh, X1, X2, 0);
    // step 3: x=[h0|obs1] (=X0, pads hold obs1), h=h2 -> h3 in X1 (X1 pads already obs2)
    gru_step<1088, 1024, false, false><<<gridG, blkG, 0, stream>>>(
        X0, 34816, PWih, X2, PWhh, nullptr, ids, bih, bhh, X2, X1, 0);
    // step 4: x=[h3|obs2] (=X1), h=h3 -> fp32 d_out (row-major)
    gru_step<1088, 1024, false, true><<<gridG, blkG, 0, stream>>>(
        X1, 34816, PWih, X1, PWhh, nullptr, ids, bih, bhh, X1, out, 1024);
}